// Round 6
// baseline (90.022 us; speedup 1.0000x reference)
//
#include <hip/hip_runtime.h>
#include <math.h>

#define DIM  4096
#define BLK  512            // 8 waves = 2 states x 4 waves; 2 waves/SIMD
#define NPAR 144

typedef float v2f __attribute__((ext_vector_type(2)));

// ---------------------------------------------------------------------------
// R18 = R13 schedule (4 reg bits, 16 amps/thread, 8 epochs/layer, 23
// restages — correctness-validated at R13) + TWO batch elements per block:
// waves 0-3 = state 0, waves 4-7 = state 1 (threadIdx bit 8), grid = B/2.
// Each SIMD hosts one wave of EACH state: two independent streams whose
// restage latency chains mutually hide (R12/R13 calibration: per-restage
// wall cost halves from 1 to 2 waves/SIMD; R14/R15 showed the second stream
// must do useful work, not redundant work).
// LDS 128 KB: per-state local Ls (32 KB, wave-private 8 KB regions) +
// per-state SINGLE-buffer global C (32 KB). Single-buffering needs a second
// __syncthreads after the global unstash (write-after-read across waves).
// All maps/gates/layouts byte-for-byte R13 (validated); AT.buf unused.
// Canonical bit b <-> python wire w = 11-b (validated R1-R13 convention).
// ---------------------------------------------------------------------------
struct Ph { int reg[4]; int wav[2]; };
struct TMap { unsigned pk[8]; unsigned short so[16]; unsigned short rn[16]; };

constexpr int REGS4[8][4] = {
  {11,0,1,2},{2,3,4,5},{5,6,7,8},{8,9,10,11},
  {10,11,0,1},{7,8,9,10},{4,5,6,7},{1,2,3,4}};
constexpr int PINS[8][2] = {
  {9,10},{9,10},{9,10},{2,3},{2,3},{2,3},{2,3},{9,10}};

constexpr Ph phaseAt(int i) {         // i = 0..24; 0 = pseudo (== epoch 0)
  Ph p = {};
  int e = (i == 0) ? 0 : (i - 1) % 8;
  for (int j = 0; j < 4; ++j) p.reg[j] = REGS4[e][j];
  p.wav[0] = PINS[e][0]; p.wav[1] = PINS[e][1];
  return p;
}
constexpr bool inArr(const int* a, int n, int b) {
  for (int i = 0; i < n; ++i) if (a[i] == b) return true;
  return false;
}
constexpr int idxOf4(const int* a, int v) {
  for (int j = 0; j < 4; ++j) if (a[j] == v) return j;
  return -1;
}
constexpr bool isLoc(int t) {
  Ph a = phaseAt(t), b = phaseAt(t + 1);
  return a.wav[0]==b.wav[0] && a.wav[1]==b.wav[1];
}
constexpr int sharedBit(Ph o, Ph n) {
  for (int j = 0; j < 4; ++j) if (inArr(n.reg, 4, o.reg[j])) return o.reg[j];
  return -1;
}

struct BuildOut { TMap m; int js, jn; bool ok; };

// GF(2)-linear canonical->slot map (R7-validated construction, widened at
// R13). Row 0 = shared reg bit (b128 pairing both sides). Rows 1..3 = lane
// bits common to both phases (bank-conflict-free b128: byte bits 4..6).
// Local: wave bits -> rows 10..11 (private 8 KB/wave region in state's Ls).
constexpr BuildOut buildT(Ph o, Ph n, bool local) {
  BuildOut R = {};
  R.ok = true;
  int s = sharedBit(o, n);
  if (s < 0) { R.ok = false; return R; }
  R.js = idxOf4(o.reg, s);
  R.jn = idxOf4(n.reg, s);
  if (R.js < 0 || R.jn < 0) { R.ok = false; return R; }
  bool lo[12] = {}, ln[12] = {};
  for (int b = 0; b < 12; ++b) {
    lo[b] = !inArr(o.reg,4,b) && !inArr(o.wav,2,b);
    ln[b] = !inArr(n.reg,4,b) && !inArr(n.wav,2,b);
  }
  int col[12] = {};
  bool uo[12] = {}, un[12] = {}, consumed[12] = {};
  col[s] = 1; consumed[s] = true;
  int row = 1;
  for (int b = 0; b < 12 && row < 4; ++b)
    if (lo[b] && ln[b] && !consumed[b]) { col[b] = 1 << row; uo[b]=un[b]=true; consumed[b]=true; ++row; }
  while (row < 4) {
    int a = -1, c = -1;
    for (int b = 0; b < 12; ++b) if (lo[b] && !uo[b] && !consumed[b]) { a = b; break; }
    for (int b = 0; b < 12; ++b) if (ln[b] && !un[b] && !consumed[b] && b != a) { c = b; break; }
    if (a < 0 || c < 0) { R.ok = false; return R; }
    col[a] |= 1 << row; col[c] |= 1 << row;
    uo[a]=true; un[c]=true; consumed[c]=true;
    ++row;
  }
  if (local) {
    for (int i = 0; i < 2; ++i) {
      if (consumed[o.wav[i]]) { R.ok = false; return R; }
      col[o.wav[i]] |= 1 << (10 + i);
      consumed[o.wav[i]] = true;
    }
    int rr = 4;
    for (int b = 0; b < 12; ++b) if (!consumed[b]) { col[b] |= 1 << rr; ++rr; }
    if (rr != 10) { R.ok = false; return R; }
  } else {
    int rr = 4;
    for (int b = 0; b < 12; ++b) if (!consumed[b]) { col[b] |= 1 << rr; ++rr; }
    if (rr != 12) { R.ok = false; return R; }
  }
  {                                     // rank-12 invertibility over GF(2)
    int pv[12] = {}, pb[12] = {};
    int nr = 0;
    for (int b = 0; b < 12; ++b) {
      int v = col[b];
      for (int k = 0; k < nr; ++k) if (v & pb[k]) v ^= pv[k];
      if (v) { pb[nr] = v & (-v); pv[nr] = v; ++nr; }
    }
    if (nr != 12) { R.ok = false; return R; }
  }
  int Lo[6] = {}, Ln6[6] = {};
  int i0 = 0, i1 = 0;
  for (int b = 0; b < 12; ++b) { if (lo[b]) Lo[i0++] = b; if (ln[b]) Ln6[i1++] = b; }
  if (i0 != 6 || i1 != 6) { R.ok = false; return R; }
  for (int i = 0; i < 8; ++i) {
    unsigned po = (i < 6) ? (unsigned)col[Lo[i]] : (unsigned)col[o.wav[i-6]];
    unsigned pn = (i < 6) ? (unsigned)col[Ln6[i]] : (unsigned)col[n.wav[i-6]];
    R.m.pk[i] = po | (pn << 16);
  }
  for (int r = 0; r < 16; ++r) {
    int a = 0, c = 0;
    for (int j = 0; j < 4; ++j)
      if ((r >> j) & 1) { a ^= col[o.reg[j]]; c ^= col[n.reg[j]]; }
    R.m.so[r] = (unsigned short)(a * 8);
    R.m.rn[r] = (unsigned short)(c * 8);
  }
  return R;
}

constexpr bool mapsEqual(const TMap& a, const TMap& b) {
  for (int i = 0; i < 8; ++i) if (a.pk[i] != b.pk[i]) return false;
  for (int r = 0; r < 16; ++r)
    if (a.so[r] != b.so[r] || a.rn[r] != b.rn[r]) return false;
  return true;
}

struct AllT { TMap t[24]; bool loc[24]; int js[24]; int jn[24]; bool ok; };
constexpr AllT buildAll() {
  AllT A = {};
  A.ok = true;
  for (int t = 0; t < 24; ++t) {
    BuildOut b = buildT(phaseAt(t), phaseAt(t + 1), isLoc(t));
    A.t[t] = b.m;
    A.ok = A.ok && b.ok;
    A.loc[t] = isLoc(t);
    A.js[t] = b.js;
    A.jn[t] = b.jn;
  }
  // transition classes repeat with period 8 (enables cached per-thread addrs)
  for (int t = 9; t < 24; ++t)
    A.ok = A.ok && mapsEqual(A.t[t], A.t[t-8]) && A.loc[t] == A.loc[t-8]
         && A.js[t] == A.js[t-8] && A.jn[t] == A.jn[t-8];
  // exactly 2 barrier restages per layer, at epoch 2->3 and 6->7
  {
    int ng = 0;
    for (int t = 1; t < 24; ++t) if (!A.loc[t]) ++ng;
    A.ok = A.ok && (ng == 6);
    for (int t = 1; t < 24; ++t) {
      bool expectGlob = (((t - 1) % 8) == 2) || (((t - 1) % 8) == 6);
      A.ok = A.ok && (A.loc[t] == !expectGlob);
    }
  }
  return A;
}
constexpr AllT AT = buildAll();
static_assert(AT.ok, "slot-map construction failed");

// ---------------- angle fetch via v_readlane --------------------------------
__device__ __forceinline__ float rlf(float v, int l) {
  return __int_as_float(__builtin_amdgcn_readlane(__float_as_int(v), l));
}
template<int AO>
__device__ __forceinline__ v2f angAt(const float (&ct)[3], const float (&st)[3]) {
  v2f a;
  a.x = rlf(ct[AO >> 6], AO & 63);
  a.y = rlf(st[AO >> 6], AO & 63);
  return a;
}

// ---------------- gates on the 16-amplitude register file -------------------
template<int J>
__device__ __forceinline__ void ry16(v2f (&z)[16], v2f a) {
  const float c = a.x, s = a.y;
  #pragma unroll
  for (int p = 0; p < 8; ++p) {
    const int r0 = ((p & ~((1 << J) - 1)) << 1) | (p & ((1 << J) - 1));
    const int r1 = r0 | (1 << J);
    v2f u = z[r0], v = z[r1];
    z[r0] = c * u - s * v;
    z[r1] = s * u + c * v;
  }
}
// CRX, off-diagonal -i*s (validated R1-R13). R17 packed form: component swap
// is register renaming (free); {s,-s} sign vector exposes v_pk_mul/v_pk_fma.
template<int JC, int JT>
__device__ __forceinline__ void crx16(v2f (&z)[16], v2f a) {
  const float c = a.x, s = a.y;
  const v2f spm = {s, -s};
  constexpr int MC = 1 << JC, MT = 1 << JT;
  constexpr int mlo = MC < MT ? MC : MT;
  constexpr int mhi = MC < MT ? MT : MC;
  #pragma unroll
  for (int p = 0; p < 4; ++p) {
    int q = ((p & ~(mlo - 1)) << 1) | (p & (mlo - 1));
    q = ((q & ~(mhi - 1)) << 1) | (q & (mhi - 1));
    const int r0 = q | MC, r1 = r0 | MT;
    v2f u = z[r0], v = z[r1];
    v2f vs = {v.y, v.x};
    v2f us = {u.y, u.x};
    z[r0] = c * u + spm * vs;
    z[r1] = c * v + spm * us;
  }
}

// Epoch gate lists. Slot j of epoch e <-> canonical bit REGS4[e][j].
// RYs first, then chain CRX links in circuit order. (R13-validated.)
template<int E, int L>
__device__ __forceinline__ void gates(v2f (&z)[16], const float (&ct)[3], const float (&st)[3]) {
#define A(k) (angAt<48 * L + (k)>(ct, st))
  if constexpr (E == 0)      { ry16<0>(z,A(0));  ry16<1>(z,A(11)); ry16<2>(z,A(10)); ry16<3>(z,A(9));
                               crx16<1,0>(z,A(12)); crx16<2,1>(z,A(13)); crx16<3,2>(z,A(14)); }
  else if constexpr (E == 1) { ry16<1>(z,A(8));  ry16<2>(z,A(7));  ry16<3>(z,A(6));
                               crx16<1,0>(z,A(15)); crx16<2,1>(z,A(16)); crx16<3,2>(z,A(17)); }
  else if constexpr (E == 2) { ry16<1>(z,A(5));  ry16<2>(z,A(4));  ry16<3>(z,A(3));
                               crx16<1,0>(z,A(18)); crx16<2,1>(z,A(19)); crx16<3,2>(z,A(20)); }
  else if constexpr (E == 3) { ry16<1>(z,A(2));  ry16<2>(z,A(1));
                               crx16<1,0>(z,A(21)); crx16<2,1>(z,A(22)); crx16<3,2>(z,A(23)); }
  else if constexpr (E == 4) { ry16<0>(z,A(25)); ry16<1>(z,A(24)); ry16<2>(z,A(35)); ry16<3>(z,A(34));
                               crx16<2,3>(z,A(36)); crx16<1,2>(z,A(37)); crx16<0,1>(z,A(38)); }
  else if constexpr (E == 5) { ry16<0>(z,A(28)); ry16<1>(z,A(27)); ry16<2>(z,A(26));
                               crx16<2,3>(z,A(39)); crx16<1,2>(z,A(40)); crx16<0,1>(z,A(41)); }
  else if constexpr (E == 6) { ry16<0>(z,A(31)); ry16<1>(z,A(30)); ry16<2>(z,A(29));
                               crx16<2,3>(z,A(42)); crx16<1,2>(z,A(43)); crx16<0,1>(z,A(44)); }
  else                       { ry16<1>(z,A(33)); ry16<2>(z,A(32));
                               crx16<2,3>(z,A(45)); crx16<1,2>(z,A(46)); crx16<0,1>(z,A(47)); }
#undef A
}

template<int T>
__device__ __forceinline__ void restage(v2f (&z)[16],
                                        const unsigned (&bo)[8], const unsigned (&bn)[8],
                                        char* Lb, char* Cb) {
  constexpr int K = (T - 1) & 7;        // maps repeat mod 8 (constexpr-checked)
  constexpr bool LOC = AT.loc[T];
  constexpr int JS = AT.js[T], JN = AT.jn[T];
  char* buf = LOC ? Lb : Cb;
  const unsigned o = bo[K], n_ = bn[K];
  // stash: 8 x ds_write_b128, pairing regs over the shared bit (slot bit 0)
  #pragma unroll
  for (int r = 0; r < 16; ++r) {
    if (r & (1 << JS)) continue;
    v2f z0 = z[r], z1 = z[r | (1 << JS)];
    float4 w; w.x = z0.x; w.y = z0.y; w.z = z1.x; w.w = z1.y;
    *(float4*)(buf + (o ^ AT.t[T].so[r])) = w;
  }
  if (LOC) {
    // same-wave LDS ops are serviced in program order (R7-validated):
    // reads queue behind writes — only a compiler fence needed.
    asm volatile("" ::: "memory");
  } else {
    __syncthreads();
  }
  // unstash: 8 x ds_read_b128
  #pragma unroll
  for (int r = 0; r < 16; ++r) {
    if (r & (1 << JN)) continue;
    float4 w = *(const float4*)(buf + (n_ ^ AT.t[T].rn[r]));
    v2f z0, z1;
    z0.x = w.x; z0.y = w.y;
    z1.x = w.z; z1.y = w.w;
    z[r] = z0;
    z[r | (1 << JN)] = z1;
  }
  if constexpr (!LOC) {
    // single-buffer global: next global stash reuses this buffer; make sure
    // every wave's reads completed before anyone can write it again.
    __syncthreads();
  }
}

template<int L>
__device__ __forceinline__ void layer(v2f (&z)[16],
                                      const unsigned (&bo)[8], const unsigned (&bn)[8],
                                      const float (&ct)[3], const float (&st)[3],
                                      char* Lb, char* Cb) {
  gates<0, L>(z, ct, st);  restage<8*L + 1>(z, bo, bn, Lb, Cb);
  gates<1, L>(z, ct, st);  restage<8*L + 2>(z, bo, bn, Lb, Cb);
  gates<2, L>(z, ct, st);  restage<8*L + 3>(z, bo, bn, Lb, Cb);
  gates<3, L>(z, ct, st);  restage<8*L + 4>(z, bo, bn, Lb, Cb);
  gates<4, L>(z, ct, st);  restage<8*L + 5>(z, bo, bn, Lb, Cb);
  gates<5, L>(z, ct, st);  restage<8*L + 6>(z, bo, bn, Lb, Cb);
  gates<6, L>(z, ct, st);  restage<8*L + 7>(z, bo, bn, Lb, Cb);
  gates<7, L>(z, ct, st);
  if constexpr (L < 2) restage<8*L + 8>(z, bo, bn, Lb, Cb);
}

__global__ __launch_bounds__(BLK) void ansatz_kernel(
    const float* __restrict__ sre, const float* __restrict__ sim,
    const float* __restrict__ params, float* __restrict__ out) {

  // Per-state buffers: Cs[state] global-restage (single-buffered, barrier
  // pair), Lss[state] local-restage (wave-private 8 KB regions). 128 KB.
  __shared__ alignas(16) v2f Cs[2][DIM], Lss[2][DIM];

  const int st8 = threadIdx.x >> 8;       // state within block (wave group)
  const int tid = threadIdx.x & 255;      // within-state thread id
  const int b = blockIdx.x * 2 + st8;     // batch element
  char* Cb = (char*)&Cs[st8][0];
  char* Lb = (char*)&Lss[st8][0];

  // ---- per-wave angle table in lane-distributed VGPRs (no LDS, no barrier)
  float ct[3], st[3];
  {
    const int lane = threadIdx.x & 63;
    #pragma unroll
    for (int j = 0; j < 3; ++j) {
      int idx = lane + 64 * j;
      int ci = (idx < NPAR) ? idx : 0;
      float th = params[(size_t)b * NPAR + ci];
      sincosf(0.5f * th, &st[j], &ct[j]);
    }
  }

  // ---- cached per-thread restage addresses (maps repeat mod 8) ----
  unsigned bo[8], bn[8];
  #pragma unroll
  for (int k = 0; k < 8; ++k) {
    unsigned acc = 0;
    #pragma unroll
    for (int i = 0; i < 8; ++i)
      acc ^= (unsigned)(-((tid >> i) & 1)) & AT.t[k + 1].pk[i];
    bo[k] = (acc & 0xfffu) << 3;
    bn[k] = ((acc >> 16) & 0xfffu) << 3;
  }

  // ---- init: direct gather in epoch-0 layout ----
  // epoch 0: reg slots {11,0,1,2} (r bit0<->amp bit11, r bits1..3<->amp
  // bits 0..2); lanes tid0..5 -> amp bits 3..8; waves tid6,7 -> bits 9,10.
  // => base = tid*8, fully coalesced float4 loads. (R13-validated.)
  v2f z[16];
  {
    const float4* pr = (const float4*)(sre + (size_t)b * DIM + (size_t)tid * 8);
    const float4* pi = (const float4*)(sim + (size_t)b * DIM + (size_t)tid * 8);
    float4 f0 = pr[0], f1 = pr[1], f2 = pr[512], f3 = pr[513];  // +512 f4 = bit 11
    float4 g0 = pi[0], g1 = pi[1], g2 = pi[512], g3 = pi[513];
    z[0].x  = f0.x; z[0].y  = g0.x;  z[2].x  = f0.y; z[2].y  = g0.y;
    z[4].x  = f0.z; z[4].y  = g0.z;  z[6].x  = f0.w; z[6].y  = g0.w;
    z[8].x  = f1.x; z[8].y  = g1.x;  z[10].x = f1.y; z[10].y = g1.y;
    z[12].x = f1.z; z[12].y = g1.z;  z[14].x = f1.w; z[14].y = g1.w;
    z[1].x  = f2.x; z[1].y  = g2.x;  z[3].x  = f2.y; z[3].y  = g2.y;
    z[5].x  = f2.z; z[5].y  = g2.z;  z[7].x  = f2.w; z[7].y  = g2.w;
    z[9].x  = f3.x; z[9].y  = g3.x;  z[11].x = f3.y; z[11].y = g3.y;
    z[13].x = f3.z; z[13].y = g3.z;  z[15].x = f3.w; z[15].y = g3.w;
  }

  layer<0>(z, bo, bn, ct, st, Lb, Cb);
  layer<1>(z, bo, bn, ct, st, Lb, Cb);
  layer<2>(z, bo, bn, ct, st, Lb, Cb);

  // ---- final: direct scatter store from epoch-7 layout ----
  // epoch 7: reg slots {1,2,3,4} (amp = base + 2*r); lanes tid0..5 -> amp
  // bits {0,5,6,7,8,11}; waves tid6,7 -> bits 9,10. (R13-validated.)
  {
    int base = (tid & 1) | ((tid & 2) << 4) | ((tid & 4) << 4)
             | ((tid & 8) << 4) | ((tid & 16) << 4) | ((tid & 32) << 6)
             | ((tid & 64) << 3) | ((tid & 128) << 3);
    v2f* o2 = (v2f*)out + (size_t)b * DIM + base;
    #pragma unroll
    for (int r = 0; r < 16; ++r)
      o2[2 * r] = z[r];
  }
}

extern "C" void kernel_launch(void* const* d_in, const int* in_sizes, int n_in,
                              void* d_out, int out_size, void* d_ws, size_t ws_size,
                              hipStream_t stream) {
  const float* sre    = (const float*)d_in[0];
  const float* sim    = (const float*)d_in[1];
  const float* params = (const float*)d_in[2];
  float* out          = (float*)d_out;

  const int B = in_sizes[0] / DIM;   // 128
  ansatz_kernel<<<B / 2, BLK, 0, stream>>>(sre, sim, params, out);
}

// Round 7
// 77.555 us; speedup vs baseline: 1.1608x; 1.1608x over previous
//
#include <hip/hip_runtime.h>
#include <math.h>

#define DIM  4096
#define BLK  512            // 8 waves; 8 amplitudes (v2f) per thread; 2 waves/SIMD
#define NPAR 144

typedef float v2f __attribute__((ext_vector_type(2)));

// ---------------------------------------------------------------------------
// R19 = R17 (best measured: 77.3; R12 structure + packed crx8) + cached
// restage addresses: the 35 transition maps repeat with period 12
// (phaseAt(T) depends only on (T-1)%12; globals per layer are even so C0/C1
// parity repeats too — both static_assert'd). Each thread computes its 12
// (bo,bn) pairs once (24 VGPRs) instead of a 9-term GF(2) XOR per restage.
// Removes ~850 VALU ops/thread from the hot path; addresses bit-identical.
// R18 lesson: grid must stay 128 (1 state/CU); 2 states/block halves CU
// count and doubles per-CU load — never again. R16 lesson: b32 lane-op
// restages 3x worse than b128 LDS. R13/R15: 2 waves/SIMD TLP load-bearing.
// ---------------------------------------------------------------------------
struct Ph { int reg[3]; int wav[3]; };
struct TMap { unsigned pk[9]; unsigned short so[8]; unsigned short rn[8]; };

constexpr int REGS[12][3] = {
  {11,0,1},{1,2,3},{3,4,5},{5,6,7},{7,8,9},{9,10,11},
  {11,0,1},{9,10,11},{7,8,9},{5,6,7},{3,4,5},{1,2,3}};

constexpr Ph phaseAt(int i) {         // i = 0..37; 0/37 = global pseudo-phase
  Ph p = {};
  if (i == 0 || i == 37) {
    p.reg[0]=0; p.reg[1]=1; p.reg[2]=2;
    p.wav[0]=9; p.wav[1]=10; p.wav[2]=11;
    return p;
  }
  int e = (i - 1) % 12;
  for (int j = 0; j < 3; ++j) p.reg[j] = REGS[e][j];
  bool A = (e <= 2) || (e >= 10);     // pin {6,7,8} else {2,3,4}
  p.wav[0] = A ? 6 : 2; p.wav[1] = A ? 7 : 3; p.wav[2] = A ? 8 : 4;
  return p;
}
constexpr bool inArr(const int* a, int n, int b) {
  for (int i = 0; i < n; ++i) if (a[i] == b) return true;
  return false;
}
constexpr int idxOf3(const int* a, int v) {
  for (int j = 0; j < 3; ++j) if (a[j] == v) return j;
  return -1;
}
constexpr bool isLoc(int t) {
  if (t == 0 || t == 36) return false;
  Ph a = phaseAt(t), b = phaseAt(t + 1);
  return a.wav[0]==b.wav[0] && a.wav[1]==b.wav[1] && a.wav[2]==b.wav[2];
}
constexpr int bufIdx(int t) {
  int k = 0;
  for (int u = 0; u <= t; ++u) if (!isLoc(u)) ++k;
  return (k + 1) & 1;
}
constexpr int sharedBit(Ph o, Ph n) {
  for (int j = 0; j < 3; ++j) if (inArr(n.reg, 3, o.reg[j])) return o.reg[j];
  return -1;
}

struct BuildOut { TMap m; int js, jn; bool ok; };

// GF(2)-linear canonical->slot map (R7-validated). Row 0 = shared reg bit
// (b128 pairing both sides). Rows 1..3 = lane bits of both phases (bank-
// conflict-free b128). Local: wave bits -> rows 9..11 (private 4 KB/wave).
constexpr BuildOut buildT(Ph o, Ph n, bool local) {
  BuildOut R = {};
  R.ok = true;
  int s = sharedBit(o, n);
  if (s < 0) { R.ok = false; return R; }
  R.js = idxOf3(o.reg, s);
  R.jn = idxOf3(n.reg, s);
  if (R.js < 0 || R.jn < 0) { R.ok = false; return R; }
  bool lo[12] = {}, ln[12] = {};
  for (int b = 0; b < 12; ++b) {
    lo[b] = !inArr(o.reg,3,b) && !inArr(o.wav,3,b);
    ln[b] = !inArr(n.reg,3,b) && !inArr(n.wav,3,b);
  }
  int col[12] = {};
  bool uo[12] = {}, un[12] = {}, consumed[12] = {};
  col[s] = 1; consumed[s] = true;
  int row = 1;
  for (int b = 0; b < 12 && row < 4; ++b)
    if (lo[b] && ln[b] && !consumed[b]) { col[b] = 1 << row; uo[b]=un[b]=true; consumed[b]=true; ++row; }
  while (row < 4) {
    int a = -1, c = -1;
    for (int b = 0; b < 12; ++b) if (lo[b] && !uo[b] && !consumed[b]) { a = b; break; }
    for (int b = 0; b < 12; ++b) if (ln[b] && !un[b] && !consumed[b] && b != a) { c = b; break; }
    if (a < 0 || c < 0) { R.ok = false; return R; }
    col[a] |= 1 << row; col[c] |= 1 << row;
    uo[a]=true; un[c]=true; consumed[c]=true;     // a still needs an identity row
    ++row;
  }
  if (local) {
    for (int i = 0; i < 3; ++i) {
      if (consumed[o.wav[i]]) { R.ok = false; return R; }
      col[o.wav[i]] |= 1 << (9 + i);
      consumed[o.wav[i]] = true;
    }
    int rr = 4;
    for (int b = 0; b < 12; ++b) if (!consumed[b]) { col[b] |= 1 << rr; ++rr; }
    if (rr != 9) { R.ok = false; return R; }
  } else {
    int rr = 4;
    for (int b = 0; b < 12; ++b) if (!consumed[b]) { col[b] |= 1 << rr; ++rr; }
    if (rr != 12) { R.ok = false; return R; }
  }
  {                                     // rank-12 invertibility over GF(2)
    int pv[12] = {}, pb[12] = {};
    int nr = 0;
    for (int b = 0; b < 12; ++b) {
      int v = col[b];
      for (int k = 0; k < nr; ++k) if (v & pb[k]) v ^= pv[k];
      if (v) { pb[nr] = v & (-v); pv[nr] = v; ++nr; }
    }
    if (nr != 12) { R.ok = false; return R; }
  }
  int Lo[6] = {}, Ln[6] = {};
  int i0 = 0, i1 = 0;
  for (int b = 0; b < 12; ++b) { if (lo[b]) Lo[i0++] = b; if (ln[b]) Ln[i1++] = b; }
  if (i0 != 6 || i1 != 6) { R.ok = false; return R; }
  for (int i = 0; i < 9; ++i) {
    unsigned po = (i < 6) ? (unsigned)col[Lo[i]] : (unsigned)col[o.wav[i-6]];
    unsigned pn = (i < 6) ? (unsigned)col[Ln[i]] : (unsigned)col[n.wav[i-6]];
    R.m.pk[i] = po | (pn << 16);
  }
  for (int r = 0; r < 8; ++r) {
    int a = 0, c = 0;
    for (int j = 0; j < 3; ++j)
      if ((r >> j) & 1) { a ^= col[o.reg[j]]; c ^= col[n.reg[j]]; }
    R.m.so[r] = (unsigned short)(a * 8);
    R.m.rn[r] = (unsigned short)(c * 8);
  }
  return R;
}

constexpr bool mapsEqual(const TMap& a, const TMap& b) {
  for (int i = 0; i < 9; ++i) if (a.pk[i] != b.pk[i]) return false;
  for (int r = 0; r < 8; ++r)
    if (a.so[r] != b.so[r] || a.rn[r] != b.rn[r]) return false;
  return true;
}

struct AllT { TMap t[37]; bool loc[37]; int buf[37]; int js[37]; int jn[37]; bool ok; };
constexpr AllT buildAll() {
  AllT A = {};
  A.ok = true;
  for (int t = 0; t < 37; ++t) {
    BuildOut b = buildT(phaseAt(t), phaseAt(t + 1), isLoc(t));
    A.t[t] = b.m;
    A.ok = A.ok && b.ok;
    A.loc[t] = isLoc(t);
    A.buf[t] = bufIdx(t);
    A.js[t] = b.js;
    A.jn[t] = b.jn;
  }
  // R19: transition classes repeat with period 12 (incl. buffer parity) —
  // enables 12-entry per-thread address cache.
  for (int t = 13; t <= 35; ++t)
    A.ok = A.ok && mapsEqual(A.t[t], A.t[t - 12]) && A.loc[t] == A.loc[t-12]
         && A.buf[t] == A.buf[t-12] && A.js[t] == A.js[t-12]
         && A.jn[t] == A.jn[t-12];
  return A;
}
constexpr AllT AT = buildAll();
static_assert(AT.ok, "slot-map construction / periodicity failed");

// ---------------- angle fetch via v_readlane --------------------------------
__device__ __forceinline__ float rlf(float v, int l) {
  return __int_as_float(__builtin_amdgcn_readlane(__float_as_int(v), l));
}
template<int AO>
__device__ __forceinline__ v2f angAt(const float (&ct)[3], const float (&st)[3]) {
  v2f a;
  a.x = rlf(ct[AO >> 6], AO & 63);
  a.y = rlf(st[AO >> 6], AO & 63);
  return a;
}

// ---------------- gates on the 8-amplitude register file --------------------
template<int J>
__device__ __forceinline__ void ry8(v2f (&z)[8], v2f a) {
  const float c = a.x, s = a.y;
  #pragma unroll
  for (int p = 0; p < 4; ++p) {
    const int r0 = ((p & ~((1 << J) - 1)) << 1) | (p & ((1 << J) - 1));
    const int r1 = r0 | (1 << J);
    v2f u = z[r0], v = z[r1];
    z[r0] = c * u - s * v;
    z[r1] = s * u + c * v;
  }
}
// CRX, off-diagonal -i*s (validated R1-R17). Packed form (R17): component
// swap is register renaming; {s,-s} sign vector exposes v_pk_mul/v_pk_fma.
template<int JC, int JT>
__device__ __forceinline__ void crx8(v2f (&z)[8], v2f a) {
  const float c = a.x, s = a.y;
  const v2f spm = {s, -s};
  constexpr int MC = 1 << JC, MT = 1 << JT;
  constexpr int mlo = MC < MT ? MC : MT;
  constexpr int mhi = MC < MT ? MT : MC;
  #pragma unroll
  for (int p = 0; p < 2; ++p) {
    int q = ((p & ~(mlo - 1)) << 1) | (p & (mlo - 1));
    q = ((q & ~(mhi - 1)) << 1) | (q & (mhi - 1));
    const int r0 = q | MC, r1 = r0 | MT;
    v2f u = z[r0], v = z[r1];
    v2f vs = {v.y, v.x};
    v2f us = {u.y, u.x};
    z[r0] = c * u + spm * vs;
    z[r1] = c * v + spm * us;
  }
}

// Epoch gate lists — verbatim from the R6-R11-validated schedule.
template<int E, int L>
__device__ __forceinline__ void gates(v2f (&z)[8], const float (&ct)[3], const float (&st)[3]) {
#define A(k) (angAt<48 * L + (k)>(ct, st))
  if constexpr (E == 0)      { ry8<0>(z,A(0));  ry8<1>(z,A(11)); ry8<2>(z,A(10));
                               crx8<1,0>(z,A(12)); crx8<2,1>(z,A(13)); }
  else if constexpr (E == 1) { ry8<1>(z,A(9));  ry8<2>(z,A(8));
                               crx8<1,0>(z,A(14)); crx8<2,1>(z,A(15)); }
  else if constexpr (E == 2) { ry8<1>(z,A(7));  ry8<2>(z,A(6));
                               crx8<1,0>(z,A(16)); crx8<2,1>(z,A(17)); }
  else if constexpr (E == 3) { ry8<1>(z,A(5));  ry8<2>(z,A(4));
                               crx8<1,0>(z,A(18)); crx8<2,1>(z,A(19)); }
  else if constexpr (E == 4) { ry8<1>(z,A(3));  ry8<2>(z,A(2));
                               crx8<1,0>(z,A(20)); crx8<2,1>(z,A(21)); }
  else if constexpr (E == 5) { ry8<1>(z,A(1));
                               crx8<1,0>(z,A(22)); crx8<2,1>(z,A(23)); }
  else if constexpr (E == 6) { ry8<0>(z,A(24)); ry8<1>(z,A(35)); ry8<2>(z,A(34));
                               crx8<1,2>(z,A(36)); crx8<0,1>(z,A(37)); }
  else if constexpr (E == 7) { ry8<0>(z,A(26)); ry8<1>(z,A(25));
                               crx8<1,2>(z,A(38)); crx8<0,1>(z,A(39)); }
  else if constexpr (E == 8) { ry8<0>(z,A(28)); ry8<1>(z,A(27));
                               crx8<1,2>(z,A(40)); crx8<0,1>(z,A(41)); }
  else if constexpr (E == 9) { ry8<0>(z,A(30)); ry8<1>(z,A(29));
                               crx8<1,2>(z,A(42)); crx8<0,1>(z,A(43)); }
  else if constexpr (E == 10){ ry8<0>(z,A(32)); ry8<1>(z,A(31));
                               crx8<1,2>(z,A(44)); crx8<0,1>(z,A(45)); }
  else                       { ry8<1>(z,A(33));
                               crx8<1,2>(z,A(46)); crx8<0,1>(z,A(47)); }
#undef A
}

template<int T>
__device__ __forceinline__ void restage(v2f (&z)[8],
                                        const unsigned (&bo)[12], const unsigned (&bn)[12],
                                        char* Lb, char* C0, char* C1) {
  constexpr int K = (T - 1) % 12;       // maps repeat mod 12 (static_assert'd)
  constexpr bool LOC = AT.loc[T];
  constexpr int JS = AT.js[T], JN = AT.jn[T];
  char* buf = LOC ? Lb : (AT.buf[T] ? C1 : C0);
  const unsigned o = bo[K], n_ = bn[K];
  // stash: 4 x ds_write_b128, pairing regs over the shared bit (slot bit 0)
  #pragma unroll
  for (int r = 0; r < 8; ++r) {
    if (r & (1 << JS)) continue;
    v2f z0 = z[r], z1 = z[r | (1 << JS)];
    float4 w; w.x = z0.x; w.y = z0.y; w.z = z1.x; w.w = z1.y;
    *(float4*)(buf + (o ^ AT.t[T].so[r])) = w;
  }
  if (LOC) {
    // same-wave LDS ops are serviced in program order (R7-validated):
    // reads queue behind writes — only a compiler fence needed.
    asm volatile("" ::: "memory");
  } else {
    __syncthreads();
  }
  // unstash: 4 x ds_read_b128
  #pragma unroll
  for (int r = 0; r < 8; ++r) {
    if (r & (1 << JN)) continue;
    float4 w = *(const float4*)(buf + (n_ ^ AT.t[T].rn[r]));
    v2f z0, z1;
    z0.x = w.x; z0.y = w.y;
    z1.x = w.z; z1.y = w.w;
    z[r] = z0;
    z[r | (1 << JN)] = z1;
  }
}

template<int L>
__device__ __forceinline__ void layer(v2f (&z)[8],
                                      const unsigned (&bo)[12], const unsigned (&bn)[12],
                                      const float (&ct)[3], const float (&st)[3],
                                      char* Lb, char* C0, char* C1) {
  gates<0, L>(z, ct, st);  restage<12*L + 1>(z, bo, bn, Lb, C0, C1);
  gates<1, L>(z, ct, st);  restage<12*L + 2>(z, bo, bn, Lb, C0, C1);
  gates<2, L>(z, ct, st);  restage<12*L + 3>(z, bo, bn, Lb, C0, C1);
  gates<3, L>(z, ct, st);  restage<12*L + 4>(z, bo, bn, Lb, C0, C1);
  gates<4, L>(z, ct, st);  restage<12*L + 5>(z, bo, bn, Lb, C0, C1);
  gates<5, L>(z, ct, st);  restage<12*L + 6>(z, bo, bn, Lb, C0, C1);
  gates<6, L>(z, ct, st);  restage<12*L + 7>(z, bo, bn, Lb, C0, C1);
  gates<7, L>(z, ct, st);  restage<12*L + 8>(z, bo, bn, Lb, C0, C1);
  gates<8, L>(z, ct, st);  restage<12*L + 9>(z, bo, bn, Lb, C0, C1);
  gates<9, L>(z, ct, st);  restage<12*L + 10>(z, bo, bn, Lb, C0, C1);
  gates<10, L>(z, ct, st); restage<12*L + 11>(z, bo, bn, Lb, C0, C1);
  gates<11, L>(z, ct, st);
  if constexpr (L < 2) restage<12*L + 12>(z, bo, bn, Lb, C0, C1);
}

__global__ __launch_bounds__(BLK) void ansatz_kernel(
    const float* __restrict__ sre, const float* __restrict__ sim,
    const float* __restrict__ params, float* __restrict__ out) {

  __shared__ alignas(16) v2f C0s[DIM], C1s[DIM], Ls[DIM];   // 3 x 32 KB

  const int b = blockIdx.x, tid = threadIdx.x;
  char* C0 = (char*)C0s;
  char* C1 = (char*)C1s;
  char* Lb = (char*)Ls;

  // ---- per-wave angle table in lane-distributed VGPRs (no LDS, no barrier)
  float ct[3], st[3];
  {
    const int lane = tid & 63;
    #pragma unroll
    for (int j = 0; j < 3; ++j) {
      int idx = lane + 64 * j;
      int ci = (idx < NPAR) ? idx : 0;
      float th = params[(size_t)b * NPAR + ci];
      sincosf(0.5f * th, &st[j], &ct[j]);
    }
  }

  // ---- cached per-thread restage addresses (maps repeat mod 12) ----
  unsigned bo[12], bn[12];
  #pragma unroll
  for (int k = 0; k < 12; ++k) {
    unsigned acc = 0;
    #pragma unroll
    for (int i = 0; i < 9; ++i)
      acc ^= (unsigned)(-((tid >> i) & 1)) & AT.t[k + 1].pk[i];
    bo[k] = (acc & 0xfffu) << 3;
    bn[k] = ((acc >> 16) & 0xfffu) << 3;
  }

  // ---- init: direct gather in epoch-0 layout ----
  // epoch 0: reg {11,0,1} (r0<->bit11, r1<->bit0, r2<->bit1);
  // lanes tid0..5 -> bits {2,3,4,5,9,10}; waves tid6..8 -> bits {6,7,8}
  v2f z[8];
  {
    int base = ((tid & 15) << 2) | ((tid & 16) << 5) | ((tid & 32) << 5)
             | (tid & 64) | (tid & 128) | (tid & 256);
    const float4* pr = (const float4*)(sre + (size_t)b * DIM + base);
    const float4* pi = (const float4*)(sim + (size_t)b * DIM + base);
    float4 f0 = pr[0], f1 = pr[512];      // +2048 amps (bit 11)
    float4 g0 = pi[0], g1 = pi[512];
    z[0].x = f0.x; z[0].y = g0.x;  z[2].x = f0.y; z[2].y = g0.y;
    z[4].x = f0.z; z[4].y = g0.z;  z[6].x = f0.w; z[6].y = g0.w;
    z[1].x = f1.x; z[1].y = g1.x;  z[3].x = f1.y; z[3].y = g1.y;
    z[5].x = f1.z; z[5].y = g1.z;  z[7].x = f1.w; z[7].y = g1.w;
  }

  layer<0>(z, bo, bn, ct, st, Lb, C0, C1);
  layer<1>(z, bo, bn, ct, st, Lb, C0, C1);
  layer<2>(z, bo, bn, ct, st, Lb, C0, C1);

  // ---- final: direct scatter store from epoch-11 layout ----
  // epoch 11: reg {1,2,3} (amp = base + 2*r); lanes tid0..5 -> bits
  // {0,4,5,9,10,11}; waves tid6..8 -> bits {6,7,8}
  {
    int base = (tid & 1) | ((tid & 2) << 3) | ((tid & 4) << 3)
             | ((tid & 8) << 6) | ((tid & 16) << 6) | ((tid & 32) << 6)
             | (tid & 64) | (tid & 128) | (tid & 256);
    v2f* o2 = (v2f*)out + (size_t)b * DIM + base;
    #pragma unroll
    for (int r = 0; r < 8; ++r)
      o2[2 * r] = z[r];
  }
}

extern "C" void kernel_launch(void* const* d_in, const int* in_sizes, int n_in,
                              void* d_out, int out_size, void* d_ws, size_t ws_size,
                              hipStream_t stream) {
  const float* sre    = (const float*)d_in[0];
  const float* sim    = (const float*)d_in[1];
  const float* params = (const float*)d_in[2];
  float* out          = (float*)d_out;

  const int B = in_sizes[0] / DIM;   // 128
  ansatz_kernel<<<B, BLK, 0, stream>>>(sre, sim, params, out);
}